// Round 8
// baseline (404.064 us; speedup 1.0000x reference)
//
#include <hip/hip_runtime.h>
#include <hip/hip_bf16.h>
#include <stdint.h>

#define NE 25690112ull   // 32*64*112*112
#define PP 12544         // 112*112
#define SS 112
#define EPSV 1e-5f

typedef __attribute__((ext_vector_type(8))) short short8v;
typedef __attribute__((ext_vector_type(4))) float float4v;

__device__ __forceinline__ unsigned short f2bf(float x){
  union { float f; uint32_t u; } v; v.f = x;
  uint32_t r = (v.u + 0x7fffu + ((v.u >> 16) & 1u)) >> 16;
  return (unsigned short)r;
}
__device__ __forceinline__ float bf2f(unsigned short u){ return __uint_as_float(((uint32_t)u) << 16); }

// ---------------- K1: conv1x1 via MFMA, pipelined multi-tile blocks ----------------
// Each block: convert weights once to LDS; loop 4 p-tiles with register prefetch
// of the next tile's X overlapping gather/MFMA/stage/store of the current tile.
__global__ __launch_bounds__(256) void k1_conv(
    const float* __restrict__ rgb, const float* __restrict__ fre,
    const float* __restrict__ wq_fad, const float* __restrict__ bq_fad,
    const float* __restrict__ wk_fad, const float* __restrict__ bk_fad,
    const float* __restrict__ wq_lfs, const float* __restrict__ bq_lfs,
    const float* __restrict__ wk_lfs, const float* __restrict__ bk_lfs,
    unsigned short* __restrict__ qF, unsigned short* __restrict__ kF,
    unsigned short* __restrict__ qL, unsigned short* __restrict__ kL,
    unsigned short* __restrict__ rgbb, unsigned short* __restrict__ freb)
{
  const int bx = blockIdx.x, b = blockIdx.y, z = blockIdx.z;
  const float* X  = z ? fre : rgb;
  const float* Wq = z ? wq_lfs : wq_fad;
  const float* Bq = z ? bq_lfs : bq_fad;
  const float* Wk = z ? wk_lfs : wk_fad;
  const float* Bk = z ? bk_lfs : bk_fad;
  unsigned short* Oq = z ? qL : qF;
  unsigned short* Ok = z ? kL : kF;
  unsigned short* Xb = z ? freb : rgbb;

  __shared__ __align__(16) unsigned short xs[64 * 260];      // 33.3 KB in/out staging
  __shared__ __align__(16) unsigned short wlds[2 * 64 * 64]; // 16 KB converted weights

  const int tid = threadIdx.x, lane = tid & 63, w = tid >> 6;
  const int lc = lane & 15, l4 = lane >> 4;

  // ---- prologue: weights -> wlds (swizzled), biases -> regs ----
  for (int i = tid; i < 2048; i += 256){
    const int arr = i >> 10, r = i & 1023;
    const int o = r >> 4, c4 = r & 15;
    const float* W = arr ? Wk : Wq;
    const float4 v = *(const float4*)(W + o*64 + c4*4);
    ushort4 s;
    s.x = f2bf(v.x); s.y = f2bf(v.y); s.z = f2bf(v.z); s.w = f2bf(v.w);
    uint32_t byteS = (uint32_t)(arr*8192 + o*128 + c4*8) ^ (uint32_t)((o & 7) << 4);
    *(ushort4*)((char*)wlds + byteS) = s;
  }
  float biasQ[4], biasK[4];
  #pragma unroll
  for (int ot = 0; ot < 4; ++ot){
    biasQ[ot] = Bq[ot*16 + lc];
    biasK[ot] = Bk[ot*16 + lc];
  }

  const int nt = min(4, 49 - bx*4);
  const size_t xbase = (size_t)b * 64 * PP;

  // ---- prefetch tile 0 ----
  float4 xr[16];
  {
    const int p0 = bx*4*256;
    #pragma unroll
    for (int i = 0; i < 16; ++i)
      xr[i] = *(const float4*)(X + xbase + (size_t)(w*16 + i)*PP + p0 + lane*4);
  }
  __syncthreads();   // wlds ready

  for (int t = 0; t < nt; ++t){
    const int p0 = (bx*4 + t)*256;

    // convert current tile; issue next tile's loads immediately after
    ushort4 sv[16];
    #pragma unroll
    for (int i = 0; i < 16; ++i){
      sv[i].x = f2bf(xr[i].x); sv[i].y = f2bf(xr[i].y);
      sv[i].z = f2bf(xr[i].z); sv[i].w = f2bf(xr[i].w);
    }
    if (t + 1 < nt){
      const int p1 = p0 + 256;
      #pragma unroll
      for (int i = 0; i < 16; ++i)
        xr[i] = *(const float4*)(X + xbase + (size_t)(w*16 + i)*PP + p1 + lane*4);
    }
    // bf16 copy store (512B/instr) + LDS staging [c][p] pitch 260
    #pragma unroll
    for (int i = 0; i < 16; ++i){
      const int c = w*16 + i;
      *(ushort4*)(Xb + xbase + (size_t)c*PP + p0 + lane*4) = sv[i];
      *(ushort4*)(&xs[c*260 + lane*4]) = sv[i];
    }
    __syncthreads();

    // gather A-frags (transpose): A[p][c]
    short8v afr[4][2];
    #pragma unroll
    for (int st = 0; st < 4; ++st){
      const int p = (st*4 + w)*16 + lc;
      #pragma unroll
      for (int ks = 0; ks < 2; ++ks){
        short8v a;
        #pragma unroll
        for (int j = 0; j < 8; ++j)
          a[j] = (short)xs[(ks*32 + l4*8 + j)*260 + p];
        afr[st][ks] = a;
      }
    }
    __syncthreads();   // xs free for D staging

    #pragma unroll
    for (int arr = 0; arr < 2; ++arr){
      unsigned short* O = arr ? Ok : Oq;
      const float* bias = arr ? biasK : biasQ;
      // weight frags from wlds
      short8v wf[4][2];
      #pragma unroll
      for (int ot = 0; ot < 4; ++ot)
        #pragma unroll
        for (int ks = 0; ks < 2; ++ks){
          uint32_t byteS = (uint32_t)(arr*8192 + (ot*16 + lc)*128 + ks*64 + l4*16)
                         ^ (uint32_t)((lc & 7) << 4);
          wf[ot][ks] = *(const short8v*)((const char*)wlds + byteS);
        }
      #pragma unroll
      for (int st = 0; st < 4; ++st){
        const int pt = (st*4 + w)*16;
        #pragma unroll
        for (int ot = 0; ot < 4; ++ot){
          float4v acc = (float4v){bias[ot], bias[ot], bias[ot], bias[ot]};
          acc = __builtin_amdgcn_mfma_f32_16x16x32_bf16(afr[st][0], wf[ot][0], acc, 0, 0, 0);
          acc = __builtin_amdgcn_mfma_f32_16x16x32_bf16(afr[st][1], wf[ot][1], acc, 0, 0, 0);
          ushort4 u;
          u.x = f2bf(acc[0]); u.y = f2bf(acc[1]); u.z = f2bf(acc[2]); u.w = f2bf(acc[3]);
          const int o = ot*16 + lc;
          uint32_t byteS = (uint32_t)(o*512 + (pt + l4*4)*2) ^ (uint32_t)((o & 7) << 4);
          *(ushort4*)((char*)xs + byteS) = u;
        }
      }
      __syncthreads();
      for (int i = tid; i < 2048; i += 256){
        const int o = i >> 5, s = i & 31;
        uint32_t byteS = (uint32_t)(o*512 + s*16) ^ (uint32_t)((o & 7) << 4);
        short8v v = *(const short8v*)((const char*)xs + byteS);
        *(short8v*)(O + ((size_t)b*64 + o)*PP + p0 + s*8) = v;
      }
      __syncthreads();
    }
  }
}

// ---------------- K2: MFMA attention v2 (unchanged from round 6) ----------------
__global__ __launch_bounds__(448) void k2_attn(
    unsigned short* __restrict__ qF, const unsigned short* __restrict__ qL,
    const unsigned short* __restrict__ kF, const unsigned short* __restrict__ kL,
    const unsigned short* __restrict__ rgbb, const unsigned short* __restrict__ freb,
    const float* __restrict__ fad_gamma, const float* __restrict__ lfs_gamma,
    float* __restrict__ stats)
{
  const int bc = blockIdx.x, c = bc & 63;
  const size_t plane = (size_t)bc * PP;
  __shared__ __align__(16) unsigned short ksF[PP + 16];
  __shared__ __align__(16) unsigned short ksL[PP + 16];
  const int tid = threadIdx.x, lane = tid & 63, w = tid >> 6;
  const int l4 = lane >> 4, lc = lane & 15;

  const unsigned short* qFp = qF + plane;
  const unsigned short* qLp = qL + plane;
  const int qrow = w*16 + lc;
  short8v aF[4], aL[4];
  #pragma unroll
  for (int ks = 0; ks < 4; ++ks){
    const int joff = ks*32 + l4*8;
    if ((ks < 3) || (l4 < 2)){
      aF[ks] = *(const short8v*)(qFp + qrow*SS + joff);
      aL[ks] = *(const short8v*)(qLp + qrow*SS + joff);
    } else {
      aF[ks] = (short8v)(short)0;
      aL[ks] = (short8v)(short)0;
    }
  }

  const uint32_t* kFu = (const uint32_t*)kF + plane/2;
  const uint32_t* kLu = (const uint32_t*)kL + plane/2;
  uint32_t* ksFw = (uint32_t*)ksF;
  uint32_t* ksLw = (uint32_t*)ksL;
  #pragma unroll
  for (int t = 0; t < 14; ++t){
    const int i = tid + t*448;
    ksFw[i] = kFu[i];
    ksLw[i] = kLu[i];
  }
  __syncthreads();

  float4v acc[7];
  #pragma unroll
  for (int ct = 0; ct < 7; ++ct) acc[ct] = (float4v)0.f;
  #pragma unroll
  for (int ks = 0; ks < 4; ++ks){
    #pragma unroll
    for (int ct = 0; ct < 7; ++ct){
      const uint32_t off = (uint32_t)((ct*16 + lc)*224 + ks*64 + l4*16);
      short8v bF = *(const short8v*)((const char*)ksF + off);
      short8v bL = *(const short8v*)((const char*)ksL + off);
      acc[ct] = __builtin_amdgcn_mfma_f32_16x16x32_bf16(aF[ks], bF, acc[ct], 0, 0, 0);
      acc[ct] = __builtin_amdgcn_mfma_f32_16x16x32_bf16(aL[ks], bL, acc[ct], 0, 0, 0);
    }
  }

  ushort4 frv[7], rgv[7];
  #pragma unroll
  for (int t = 0; t < 7; ++t){
    const int i4 = tid + t*448;
    frv[t] = *(const ushort4*)(freb + plane + (size_t)i4*4);
    rgv[t] = *(const ushort4*)(rgbb + plane + (size_t)i4*4);
  }

  const float sF = 2.f/(1.f + __expf(-fad_gamma[0])) - 1.f;
  const float sL = 2.f/(1.f + __expf(-lfs_gamma[0])) - 1.f;
  unsigned short* attnP = qF + plane;
  unsigned short* alin = ksF;

  __syncthreads();
  #pragma unroll
  for (int r = 0; r < 4; ++r){
    const int i = w*16 + l4*4 + r;
    float v[7];
    #pragma unroll
    for (int ct = 0; ct < 7; ++ct) v[ct] = acc[ct][r];
    float m = fmaxf(fmaxf(fmaxf(v[0],v[1]),fmaxf(v[2],v[3])), fmaxf(fmaxf(v[4],v[5]),v[6]));
    #pragma unroll
    for (int off = 8; off; off >>= 1) m = fmaxf(m, __shfl_xor(m, off, 64));
    float e[7]; float s = 0.f;
    #pragma unroll
    for (int ct = 0; ct < 7; ++ct){ e[ct] = __expf(v[ct] - m); s += e[ct]; }
    #pragma unroll
    for (int off = 8; off; off >>= 1) s += __shfl_xor(s, off, 64);
    const float inv = 1.f / s;
    #pragma unroll
    for (int ct = 0; ct < 7; ++ct)
      alin[i*SS + ct*16 + lc] = f2bf(e[ct] * inv);
  }
  __syncthreads();

  float ls1 = 0.f, lq1 = 0.f, ls2 = 0.f, lq2 = 0.f;
  #pragma unroll
  for (int t = 0; t < 7; ++t){
    const int i4 = tid + t*448;
    ushort4 av = *(const ushort4*)(alin + i4*4);
    *(ushort4*)(attnP + (size_t)i4*4) = av;
    const unsigned short* ap = &av.x;
    const unsigned short* fp = &frv[t].x;
    const unsigned short* rp = &rgv[t].x;
    #pragma unroll
    for (int j = 0; j < 4; ++j){
      float a = bf2f(ap[j]);
      float v1 = bf2f(fp[j]) * a * sL;
      float v2 = bf2f(rp[j]) * a * sF;
      ls1 += v1; lq1 += v1*v1; ls2 += v2; lq2 += v2*v2;
    }
  }
  #pragma unroll
  for (int off = 32; off; off >>= 1){
    ls1 += __shfl_xor(ls1, off, 64);
    lq1 += __shfl_xor(lq1, off, 64);
    ls2 += __shfl_xor(ls2, off, 64);
    lq2 += __shfl_xor(lq2, off, 64);
  }
  if (lane == 0){
    atomicAdd(&stats[c],       ls1);
    atomicAdd(&stats[64 + c],  lq1);
    atomicAdd(&stats[128 + c], ls2);
    atomicAdd(&stats[192 + c], lq2);
  }
}

// ---------------- K3: bn1 stats -> affine ----------------
__global__ void k3_affine1(const float* __restrict__ stats,
    const float* __restrict__ fad_cw, const float* __restrict__ fad_bg, const float* __restrict__ fad_bb,
    const float* __restrict__ lfs_cw, const float* __restrict__ lfs_bg, const float* __restrict__ lfs_bb,
    float* __restrict__ AB)
{
  int c = threadIdx.x;
  if (c >= 64) return;
  const float n = 401408.f;
  {
    float m1 = stats[c]/n, v1 = stats[64+c]/n - (stats[c]/n)*(stats[c]/n);
    float cw = fad_cw[c], g = fad_bg[c];
    float rs = rsqrtf(cw*cw*v1 + EPSV);
    AB[c]      = cw*rs*g;
    AB[64 + c] = -cw*m1*rs*g + fad_bb[c];
  }
  {
    float m2 = stats[128+c]/n, v2 = stats[192+c]/n - (stats[128+c]/n)*(stats[128+c]/n);
    float cw = lfs_cw[c], g = lfs_bg[c];
    float rs = rsqrtf(cw*cw*v2 + EPSV);
    AB[128 + c] = cw*rs*g;
    AB[192 + c] = -cw*m2*rs*g + lfs_bb[c];
  }
}

// ---------------- K4: fused y (bf16 out) + pooling + per-plane stats ----------------
__global__ __launch_bounds__(512) void k4_fuse(
    const unsigned short* __restrict__ attn,
    const unsigned short* __restrict__ rgbb, const unsigned short* __restrict__ freb,
    const float* __restrict__ AB1,
    const float* __restrict__ fad_gamma, const float* __restrict__ lfs_gamma,
    unsigned short* __restrict__ ybf, unsigned short* __restrict__ ybl,
    float* __restrict__ avgstat, float* __restrict__ maxstat,
    float4* __restrict__ planeStats)
{
  const int bc = blockIdx.x, b = bc >> 6, c = bc & 63;
  const size_t plane = (size_t)bc * PP;
  __shared__ unsigned short ys[2][112][113];
  __shared__ float redA[8][4];
  __shared__ float redS[8], redM[8];
  const int tid = threadIdx.x, lane = tid & 63, w = tid >> 6;
  const float sF = 2.f/(1.f + __expf(-fad_gamma[0])) - 1.f;
  const float sL = 2.f/(1.f + __expf(-lfs_gamma[0])) - 1.f;
  const float A1 = AB1[c], B1 = AB1[64+c], A2 = AB1[128+c], B2 = AB1[192+c];
  float s0 = 0.f, q0 = 0.f, s1 = 0.f, q1 = 0.f;

  for (int i4 = tid; i4 < 3136; i4 += 512){
    ushort4 av = *(const ushort4*)(attn + plane + (size_t)i4*4);
    ushort4 rg = *(const ushort4*)(rgbb + plane + (size_t)i4*4);
    ushort4 fr = *(const ushort4*)(freb + plane + (size_t)i4*4);
    float aa[4] = {bf2f(av.x), bf2f(av.y), bf2f(av.z), bf2f(av.w)};
    float rr[4] = {bf2f(rg.x), bf2f(rg.y), bf2f(rg.z), bf2f(rg.w)};
    float ff[4] = {bf2f(fr.x), bf2f(fr.y), bf2f(fr.z), bf2f(fr.w)};
    float y0[4], y1[4];
    ushort4 o0, o1;
    unsigned short* p0 = &o0.x; unsigned short* p1 = &o1.x;
    #pragma unroll
    for (int j = 0; j < 4; ++j){
      float t1 = ff[j]*aa[j]*sL;
      float t2 = rr[j]*aa[j]*sF;
      y0[j] = rr[j] + A1*t1 + B1;
      y1[j] = ff[j] + A2*t2 + B2;
      s0 += y0[j]; q0 += y0[j]*y0[j];
      s1 += y1[j]; q1 += y1[j]*y1[j];
      p0[j] = f2bf(y0[j]);
      p1[j] = f2bf(y1[j]);
    }
    *(ushort4*)(ybf + plane + (size_t)i4*4) = o0;
    *(ushort4*)(ybl + plane + (size_t)i4*4) = o1;
    int r = i4 / 28, c0 = (i4 % 28) * 4;
    #pragma unroll
    for (int j = 0; j < 4; ++j){
      ys[0][r][c0+j] = p0[j];
      ys[1][r][c0+j] = p1[j];
    }
  }
  #pragma unroll
  for (int off = 32; off; off >>= 1){
    s0 += __shfl_xor(s0, off, 64); q0 += __shfl_xor(q0, off, 64);
    s1 += __shfl_xor(s1, off, 64); q1 += __shfl_xor(q1, off, 64);
  }
  if (lane == 0){ redA[w][0] = s0; redA[w][1] = q0; redA[w][2] = s1; redA[w][3] = q1; }
  __syncthreads();
  if (tid == 0){
    float a0=0,a1=0,a2=0,a3=0;
    for (int i = 0; i < 8; ++i){ a0+=redA[i][0]; a1+=redA[i][1]; a2+=redA[i][2]; a3+=redA[i][3]; }
    float4 ps = {a0,a1,a2,a3};
    planeStats[bc] = ps;
  }
  __syncthreads();

  const int kk[3] = {3,5,7};
  const int gg[3] = {37,22,16};
  for (int pl = 0; pl < 2; ++pl){
    const int cc = pl*64 + c;
    for (int ki = 0; ki < 3; ++ki){
      const int k = kk[ki], g = gg[ki];
      float sumAll = 0.f, mx = -3.0e38f;
      for (int win = tid; win < g*g; win += 512){
        int wy = win / g, wx = win % g;
        float s = 0.f;
        for (int dy = 0; dy < k; ++dy)
          for (int dx = 0; dx < k; ++dx)
            s += bf2f(ys[pl][wy*k+dy][wx*k+dx]);
        sumAll += s; mx = fmaxf(mx, s);
      }
      #pragma unroll
      for (int off = 32; off; off >>= 1){
        sumAll += __shfl_xor(sumAll, off, 64);
        mx = fmaxf(mx, __shfl_xor(mx, off, 64));
      }
      if (lane == 0){ redS[w] = sumAll; redM[w] = mx; }
      __syncthreads();
      if (tid == 0){
        float st = 0.f, mt = -3.0e38f;
        for (int i = 0; i < 8; ++i){ st += redS[i]; mt = fmaxf(mt, redM[i]); }
        int idx = (b*128 + cc)*3 + ki;
        avgstat[idx] = st / (float)(k*k*g*g);
        maxstat[idx] = mt / (float)(k*k);
      }
      __syncthreads();
    }
  }
}

// ---------------- K6: channel-attention MLP ----------------
__global__ void k6_mlp(const float* __restrict__ avgstat, const float* __restrict__ maxstat,
    const float* __restrict__ lin1, const float* __restrict__ lin2,
    const float* __restrict__ w1, const float* __restrict__ w2,
    float* __restrict__ ca)
{
  const int b = blockIdx.x, tid = threadIdx.x; // 128 threads
  __shared__ float sa[128], sm[128], hA[16], hM[16];
  int idx = (b*128 + tid)*3;
  sa[tid] = avgstat[idx]*lin1[0] + avgstat[idx+1]*lin1[1] + avgstat[idx+2]*lin1[2];
  sm[tid] = maxstat[idx]*lin2[0] + maxstat[idx+1]*lin2[1] + maxstat[idx+2]*lin2[2];
  __syncthreads();
  if (tid < 16){
    float ha = 0.f, hm = 0.f;
    for (int c2 = 0; c2 < 128; ++c2){
      ha += w1[tid*128 + c2]*sa[c2];
      hm += w1[tid*128 + c2]*sm[c2];
    }
    hA[tid] = fmaxf(ha, 0.f); hM[tid] = fmaxf(hm, 0.f);
  }
  __syncthreads();
  float o = 0.f;
  for (int r = 0; r < 16; ++r) o += w2[tid*16 + r]*(hA[r] + hM[r]);
  ca[b*128 + tid] = 1.f/(1.f + __expf(-o));
}

// ---------------- K8: final bn affine from per-plane stats + ca ----------------
__global__ void k8_affineF(const float4* __restrict__ planeStats, const float* __restrict__ ca,
    const float* __restrict__ rgb_cw, const float* __restrict__ rgb_bg, const float* __restrict__ rgb_bb,
    const float* __restrict__ fre_cw, const float* __restrict__ fre_bg, const float* __restrict__ fre_bb,
    float* __restrict__ ABF)
{
  int t = threadIdx.x;
  if (t >= 128) return;
  int z = t >> 6, c = t & 63;
  float S = 0.f, Q = 0.f;
  for (int b = 0; b < 32; ++b){
    float4 ps = planeStats[b*64 + c];
    float sc = ca[b*128 + t];
    float sp = z ? ps.z : ps.x;
    float qp = z ? ps.w : ps.y;
    S += sc*sp; Q += sc*sc*qp;
  }
  const float n = 401408.f;
  float m = S/n, v = Q/n - m*m;
  float cw = z ? fre_cw[c] : rgb_cw[c];
  float g  = z ? fre_bg[c] : rgb_bg[c];
  float bb = z ? fre_bb[c] : rgb_bb[c];
  float rs = rsqrtf(cw*cw*v + EPSV);
  ABF[z*128 + c]      = cw*rs*g;
  ABF[z*128 + 64 + c] = -cw*m*rs*g + bb;
}

// ---------------- K9: out = y*(1 + A*ca) + B (bf16 y in, fp32 out) ----------------
__global__ __launch_bounds__(256) void k9_out(
    const unsigned short* __restrict__ ybf, const unsigned short* __restrict__ ybl,
    const float* __restrict__ ca, const float* __restrict__ ABF,
    float* __restrict__ out)
{
  const int c = blockIdx.x, b = blockIdx.y, z = blockIdx.z;
  const size_t plane = ((size_t)b*64 + c)*PP;
  const unsigned short* y = z ? ybl : ybf;
  float* o = out + (z ? NE : 0) + plane;
  const float sc = ca[b*128 + z*64 + c];
  const float A = ABF[z*128 + c], Bv = ABF[z*128 + 64 + c];
  const float mul = 1.f + A*sc;
  for (int i8 = threadIdx.x; i8 < 1568; i8 += 256){
    short8v yv = *(const short8v*)(y + plane + (size_t)i8*8);
    float4 o0, o1;
    o0.x = bf2f((unsigned short)yv[0])*mul + Bv;
    o0.y = bf2f((unsigned short)yv[1])*mul + Bv;
    o0.z = bf2f((unsigned short)yv[2])*mul + Bv;
    o0.w = bf2f((unsigned short)yv[3])*mul + Bv;
    o1.x = bf2f((unsigned short)yv[4])*mul + Bv;
    o1.y = bf2f((unsigned short)yv[5])*mul + Bv;
    o1.z = bf2f((unsigned short)yv[6])*mul + Bv;
    o1.w = bf2f((unsigned short)yv[7])*mul + Bv;
    *(float4*)(&o[(size_t)i8*8])     = o0;
    *(float4*)(&o[(size_t)i8*8 + 4]) = o1;
  }
}

extern "C" void kernel_launch(void* const* d_in, const int* in_sizes, int n_in,
                              void* d_out, int out_size, void* d_ws, size_t ws_size,
                              hipStream_t stream)
{
  (void)in_sizes; (void)n_in; (void)out_size; (void)ws_size;
  const float* rgb      = (const float*)d_in[0];
  const float* fre      = (const float*)d_in[1];
  const float* wq_fad   = (const float*)d_in[2];
  const float* bq_fad   = (const float*)d_in[3];
  const float* wq_lfs   = (const float*)d_in[4];
  const float* bq_lfs   = (const float*)d_in[5];
  const float* wk_fad   = (const float*)d_in[6];
  const float* bk_fad   = (const float*)d_in[7];
  const float* wk_lfs   = (const float*)d_in[8];
  const float* bk_lfs   = (const float*)d_in[9];
  const float* fad_gamma= (const float*)d_in[10];
  const float* lfs_gamma= (const float*)d_in[11];
  const float* fad_cw   = (const float*)d_in[12];
  const float* fad_bg   = (const float*)d_in[14];
  const float* fad_bb   = (const float*)d_in[15];
  const float* lfs_cw   = (const float*)d_in[16];
  const float* lfs_bg   = (const float*)d_in[18];
  const float* lfs_bb   = (const float*)d_in[19];
  const float* lin1_w   = (const float*)d_in[20];
  const float* lin2_w   = (const float*)d_in[21];
  const float* mlp_w1   = (const float*)d_in[22];
  const float* mlp_w2   = (const float*)d_in[23];
  const float* rgb_cw   = (const float*)d_in[24];
  const float* rgb_bg   = (const float*)d_in[26];
  const float* rgb_bb   = (const float*)d_in[27];
  const float* fre_cw   = (const float*)d_in[28];
  const float* fre_bg   = (const float*)d_in[30];
  const float* fre_bb   = (const float*)d_in[31];

  char* ws = (char*)d_ws;
  unsigned short* qF = (unsigned short*)(ws);          // becomes attn after k2
  unsigned short* qL = (unsigned short*)(ws + 2*NE);
  unsigned short* kF = (unsigned short*)(ws + 4*NE);   // becomes y_fad (bf16) after k4
  unsigned short* kL = (unsigned short*)(ws + 6*NE);   // becomes y_lfs (bf16) after k4
  float* sbase = (float*)(ws + 8*NE);
  float* stats      = sbase;               // [0..255]   bn1 atomics (memset)
  float* AB1        = sbase + 256;
  float* avgstat    = sbase + 512;
  float* maxstat    = sbase + 12800;
  float* ca         = sbase + 25088;
  float* ABF        = sbase + 29184;
  float4* planeStats= (float4*)(sbase + 29440);
  unsigned short* rgbb = (unsigned short*)d_out;
  unsigned short* freb = (unsigned short*)d_out + NE;

  hipMemsetAsync(stats, 0, 256*sizeof(float), stream);

  k1_conv<<<dim3(13,32,2), dim3(256), 0, stream>>>(rgb, fre,
      wq_fad, bq_fad, wk_fad, bk_fad, wq_lfs, bq_lfs, wk_lfs, bk_lfs,
      qF, kF, qL, kL, rgbb, freb);
  k2_attn<<<dim3(2048), dim3(448), 0, stream>>>(qF, qL, kF, kL,
      rgbb, freb, fad_gamma, lfs_gamma, stats);
  k3_affine1<<<dim3(1), dim3(64), 0, stream>>>(stats,
      fad_cw, fad_bg, fad_bb, lfs_cw, lfs_bg, lfs_bb, AB1);
  k4_fuse<<<dim3(2048), dim3(512), 0, stream>>>((const unsigned short*)qF,
      rgbb, freb, AB1, fad_gamma, lfs_gamma, kF, kL, avgstat, maxstat, planeStats);
  k6_mlp<<<dim3(32), dim3(128), 0, stream>>>(avgstat, maxstat,
      lin1_w, lin2_w, mlp_w1, mlp_w2, ca);
  k8_affineF<<<dim3(1), dim3(128), 0, stream>>>(planeStats, ca,
      rgb_cw, rgb_bg, rgb_bb, fre_cw, fre_bg, fre_bb, ABF);
  k9_out<<<dim3(64,32,2), dim3(256), 0, stream>>>(kF, kL, ca, ABF,
      (float*)d_out);
}

// Round 9
// 401.312 us; speedup vs baseline: 1.0069x; 1.0069x over previous
//
#include <hip/hip_runtime.h>
#include <hip/hip_bf16.h>
#include <stdint.h>

#define NE 25690112ull   // 32*64*112*112
#define PP 12544         // 112*112
#define SS 112
#define EPSV 1e-5f

typedef __attribute__((ext_vector_type(8))) short short8v;
typedef __attribute__((ext_vector_type(4))) float float4v;

__device__ __forceinline__ unsigned short f2bf(float x){
  union { float f; uint32_t u; } v; v.f = x;
  uint32_t r = (v.u + 0x7fffu + ((v.u >> 16) & 1u)) >> 16;
  return (unsigned short)r;
}
__device__ __forceinline__ float bf2f(unsigned short u){ return __uint_as_float(((uint32_t)u) << 16); }

// ---------------- K1: conv1x1 via MFMA (R6 structure, copies dropped) ----------------
__global__ __launch_bounds__(256) void k1_conv(
    const float* __restrict__ rgb, const float* __restrict__ fre,
    const float* __restrict__ wq_fad, const float* __restrict__ bq_fad,
    const float* __restrict__ wk_fad, const float* __restrict__ bk_fad,
    const float* __restrict__ wq_lfs, const float* __restrict__ bq_lfs,
    const float* __restrict__ wk_lfs, const float* __restrict__ bk_lfs,
    unsigned short* __restrict__ qF, unsigned short* __restrict__ kF,
    unsigned short* __restrict__ qL, unsigned short* __restrict__ kL)
{
  const int bx = blockIdx.x, b = blockIdx.y, z = blockIdx.z;
  const float* X  = z ? fre : rgb;
  const float* Wq = z ? wq_lfs : wq_fad;
  const float* Bq = z ? bq_lfs : bq_fad;
  const float* Wk = z ? wk_lfs : wk_fad;
  const float* Bk = z ? bk_lfs : bk_fad;
  unsigned short* Oq = z ? qL : qF;
  unsigned short* Ok = z ? kL : kF;

  __shared__ __align__(16) unsigned short xs[64 * 260];

  const int tid = threadIdx.x, lane = tid & 63, w = tid >> 6;
  const int lc = lane & 15, l4 = lane >> 4;

  // ---- Phase A: row-contiguous loads (1KB/instr) -> LDS [c][p] pitch 260 ----
  const int p0 = bx*256;
  const size_t xbase = (size_t)b * 64 * PP;
  #pragma unroll
  for (int i = 0; i < 16; ++i){
    const int c = w*16 + i;
    const size_t gof = xbase + (size_t)c*PP + p0 + lane*4;
    float4 xv = *(const float4*)(X + gof);
    ushort4 s;
    s.x = f2bf(xv.x); s.y = f2bf(xv.y); s.z = f2bf(xv.z); s.w = f2bf(xv.w);
    *(ushort4*)(&xs[c*260 + lane*4]) = s;
  }
  __syncthreads();

  // ---- Phase B: gather A-frags (transpose) ----
  short8v afr[4][2];
  #pragma unroll
  for (int t = 0; t < 4; ++t){
    const int p = (t*4 + w)*16 + lc;
    #pragma unroll
    for (int ks = 0; ks < 2; ++ks){
      short8v a;
      #pragma unroll
      for (int j = 0; j < 8; ++j)
        a[j] = (short)xs[(ks*32 + l4*8 + j)*260 + p];
      afr[t][ks] = a;
    }
  }
  __syncthreads();

  // ---- Phase C/D: per {Q,K}: MFMA -> D to LDS [o][256p] -> 512B-coalesced store
  #pragma unroll
  for (int arr = 0; arr < 2; ++arr){
    const float* W = arr ? Wk : Wq;
    const float* Bi = arr ? Bk : Bq;
    unsigned short* O = arr ? Ok : Oq;
    short8v wf[4][2];
    float bias[4];
    #pragma unroll
    for (int ot = 0; ot < 4; ++ot){
      bias[ot] = Bi[ot*16 + lc];
      #pragma unroll
      for (int ks = 0; ks < 2; ++ks){
        const int base = (ot*16 + lc)*64 + ks*32 + l4*8;
        const float4 q0 = *(const float4*)(W + base);
        const float4 q1 = *(const float4*)(W + base + 4);
        short8v v;
        v[0]=(short)f2bf(q0.x); v[1]=(short)f2bf(q0.y); v[2]=(short)f2bf(q0.z); v[3]=(short)f2bf(q0.w);
        v[4]=(short)f2bf(q1.x); v[5]=(short)f2bf(q1.y); v[6]=(short)f2bf(q1.z); v[7]=(short)f2bf(q1.w);
        wf[ot][ks] = v;
      }
    }
    #pragma unroll
    for (int t = 0; t < 4; ++t){
      const int pt = (t*4 + w)*16;
      #pragma unroll
      for (int ot = 0; ot < 4; ++ot){
        float4v acc = (float4v){bias[ot], bias[ot], bias[ot], bias[ot]};
        acc = __builtin_amdgcn_mfma_f32_16x16x32_bf16(afr[t][0], wf[ot][0], acc, 0, 0, 0);
        acc = __builtin_amdgcn_mfma_f32_16x16x32_bf16(afr[t][1], wf[ot][1], acc, 0, 0, 0);
        ushort4 u;
        u.x = f2bf(acc[0]); u.y = f2bf(acc[1]); u.z = f2bf(acc[2]); u.w = f2bf(acc[3]);
        const int o = ot*16 + lc;
        uint32_t byteS = (uint32_t)(o*512 + (pt + l4*4)*2) ^ (uint32_t)((o & 7) << 4);
        *(ushort4*)((char*)xs + byteS) = u;
      }
    }
    __syncthreads();
    for (int i = tid; i < 2048; i += 256){
      const int o = i >> 5, s = i & 31;
      uint32_t byteS = (uint32_t)(o*512 + s*16) ^ (uint32_t)((o & 7) << 4);
      short8v v = *(const short8v*)((const char*)xs + byteS);
      *(short8v*)(O + ((size_t)b*64 + o)*PP + p0 + s*8) = v;
    }
    __syncthreads();
  }
}

// ---------------- K2: MFMA attention (fp32 stat reads) ----------------
__global__ __launch_bounds__(448) void k2_attn(
    unsigned short* __restrict__ qF, const unsigned short* __restrict__ qL,
    const unsigned short* __restrict__ kF, const unsigned short* __restrict__ kL,
    const float* __restrict__ rgb, const float* __restrict__ fre,
    const float* __restrict__ fad_gamma, const float* __restrict__ lfs_gamma,
    float* __restrict__ stats)
{
  const int bc = blockIdx.x, c = bc & 63;
  const size_t plane = (size_t)bc * PP;
  __shared__ __align__(16) unsigned short ksF[PP + 16];
  __shared__ __align__(16) unsigned short ksL[PP + 16];
  const int tid = threadIdx.x, lane = tid & 63, w = tid >> 6;
  const int l4 = lane >> 4, lc = lane & 15;

  const unsigned short* qFp = qF + plane;
  const unsigned short* qLp = qL + plane;
  const int qrow = w*16 + lc;
  short8v aF[4], aL[4];
  #pragma unroll
  for (int ks = 0; ks < 4; ++ks){
    const int joff = ks*32 + l4*8;
    if ((ks < 3) || (l4 < 2)){
      aF[ks] = *(const short8v*)(qFp + qrow*SS + joff);
      aL[ks] = *(const short8v*)(qLp + qrow*SS + joff);
    } else {
      aF[ks] = (short8v)(short)0;
      aL[ks] = (short8v)(short)0;
    }
  }

  const uint32_t* kFu = (const uint32_t*)kF + plane/2;
  const uint32_t* kLu = (const uint32_t*)kL + plane/2;
  uint32_t* ksFw = (uint32_t*)ksF;
  uint32_t* ksLw = (uint32_t*)ksL;
  #pragma unroll
  for (int t = 0; t < 14; ++t){
    const int i = tid + t*448;
    ksFw[i] = kFu[i];
    ksLw[i] = kLu[i];
  }
  __syncthreads();

  float4v acc[7];
  #pragma unroll
  for (int ct = 0; ct < 7; ++ct) acc[ct] = (float4v)0.f;
  #pragma unroll
  for (int ks = 0; ks < 4; ++ks){
    #pragma unroll
    for (int ct = 0; ct < 7; ++ct){
      const uint32_t off = (uint32_t)((ct*16 + lc)*224 + ks*64 + l4*16);
      short8v bF = *(const short8v*)((const char*)ksF + off);
      short8v bL = *(const short8v*)((const char*)ksL + off);
      acc[ct] = __builtin_amdgcn_mfma_f32_16x16x32_bf16(aF[ks], bF, acc[ct], 0, 0, 0);
      acc[ct] = __builtin_amdgcn_mfma_f32_16x16x32_bf16(aL[ks], bL, acc[ct], 0, 0, 0);
    }
  }

  const float sF = 2.f/(1.f + __expf(-fad_gamma[0])) - 1.f;
  const float sL = 2.f/(1.f + __expf(-lfs_gamma[0])) - 1.f;
  unsigned short* attnP = qF + plane;
  unsigned short* alin = ksF;

  __syncthreads();
  #pragma unroll
  for (int r = 0; r < 4; ++r){
    const int i = w*16 + l4*4 + r;
    float v[7];
    #pragma unroll
    for (int ct = 0; ct < 7; ++ct) v[ct] = acc[ct][r];
    float m = fmaxf(fmaxf(fmaxf(v[0],v[1]),fmaxf(v[2],v[3])), fmaxf(fmaxf(v[4],v[5]),v[6]));
    #pragma unroll
    for (int off = 8; off; off >>= 1) m = fmaxf(m, __shfl_xor(m, off, 64));
    float e[7]; float s = 0.f;
    #pragma unroll
    for (int ct = 0; ct < 7; ++ct){ e[ct] = __expf(v[ct] - m); s += e[ct]; }
    #pragma unroll
    for (int off = 8; off; off >>= 1) s += __shfl_xor(s, off, 64);
    const float inv = 1.f / s;
    #pragma unroll
    for (int ct = 0; ct < 7; ++ct)
      alin[i*SS + ct*16 + lc] = f2bf(e[ct] * inv);
  }
  __syncthreads();

  // coalesced pass: attn write + stats from fp32 inputs (L3-resident)
  float ls1 = 0.f, lq1 = 0.f, ls2 = 0.f, lq2 = 0.f;
  #pragma unroll
  for (int t = 0; t < 7; ++t){
    const int i4 = tid + t*448;
    ushort4 av = *(const ushort4*)(alin + i4*4);
    *(ushort4*)(attnP + (size_t)i4*4) = av;
    float4 fr = *(const float4*)(fre + plane + (size_t)i4*4);
    float4 rg = *(const float4*)(rgb + plane + (size_t)i4*4);
    const unsigned short* ap = &av.x;
    const float fp[4] = {fr.x, fr.y, fr.z, fr.w};
    const float rp[4] = {rg.x, rg.y, rg.z, rg.w};
    #pragma unroll
    for (int j = 0; j < 4; ++j){
      float a = bf2f(ap[j]);
      float v1 = fp[j] * a * sL;
      float v2 = rp[j] * a * sF;
      ls1 += v1; lq1 += v1*v1; ls2 += v2; lq2 += v2*v2;
    }
  }
  #pragma unroll
  for (int off = 32; off; off >>= 1){
    ls1 += __shfl_xor(ls1, off, 64);
    lq1 += __shfl_xor(lq1, off, 64);
    ls2 += __shfl_xor(ls2, off, 64);
    lq2 += __shfl_xor(lq2, off, 64);
  }
  if (lane == 0){
    atomicAdd(&stats[c],       ls1);
    atomicAdd(&stats[64 + c],  lq1);
    atomicAdd(&stats[128 + c], ls2);
    atomicAdd(&stats[192 + c], lq2);
  }
}

// ---------------- K3: bn1 stats -> affine ----------------
__global__ void k3_affine1(const float* __restrict__ stats,
    const float* __restrict__ fad_cw, const float* __restrict__ fad_bg, const float* __restrict__ fad_bb,
    const float* __restrict__ lfs_cw, const float* __restrict__ lfs_bg, const float* __restrict__ lfs_bb,
    float* __restrict__ AB)
{
  int c = threadIdx.x;
  if (c >= 64) return;
  const float n = 401408.f;
  {
    float m1 = stats[c]/n, v1 = stats[64+c]/n - (stats[c]/n)*(stats[c]/n);
    float cw = fad_cw[c], g = fad_bg[c];
    float rs = rsqrtf(cw*cw*v1 + EPSV);
    AB[c]      = cw*rs*g;
    AB[64 + c] = -cw*m1*rs*g + fad_bb[c];
  }
  {
    float m2 = stats[128+c]/n, v2 = stats[192+c]/n - (stats[128+c]/n)*(stats[128+c]/n);
    float cw = lfs_cw[c], g = lfs_bg[c];
    float rs = rsqrtf(cw*cw*v2 + EPSV);
    AB[128 + c] = cw*rs*g;
    AB[192 + c] = -cw*m2*rs*g + lfs_bb[c];
  }
}

// ---------------- K4: y computed in-flight (NOT stored) + pooling + plane stats ----
__global__ __launch_bounds__(512) void k4_fuse(
    const unsigned short* __restrict__ attn,
    const float* __restrict__ rgb, const float* __restrict__ fre,
    const float* __restrict__ AB1,
    const float* __restrict__ fad_gamma, const float* __restrict__ lfs_gamma,
    float* __restrict__ avgstat, float* __restrict__ maxstat,
    float4* __restrict__ planeStats)
{
  const int bc = blockIdx.x, b = bc >> 6, c = bc & 63;
  const size_t plane = (size_t)bc * PP;
  __shared__ unsigned short ys[2][112][113];
  __shared__ float redA[8][4];
  __shared__ float redS[8], redM[8];
  const int tid = threadIdx.x, lane = tid & 63, w = tid >> 6;
  const float sF = 2.f/(1.f + __expf(-fad_gamma[0])) - 1.f;
  const float sL = 2.f/(1.f + __expf(-lfs_gamma[0])) - 1.f;
  const float A1 = AB1[c], B1 = AB1[64+c], A2 = AB1[128+c], B2 = AB1[192+c];
  float s0 = 0.f, q0 = 0.f, s1 = 0.f, q1 = 0.f;

  for (int i4 = tid; i4 < 3136; i4 += 512){
    ushort4 av = *(const ushort4*)(attn + plane + (size_t)i4*4);
    float4 rg = *(const float4*)(rgb + plane + (size_t)i4*4);
    float4 fr = *(const float4*)(fre + plane + (size_t)i4*4);
    float aa[4] = {bf2f(av.x), bf2f(av.y), bf2f(av.z), bf2f(av.w)};
    float rr[4] = {rg.x, rg.y, rg.z, rg.w};
    float ff[4] = {fr.x, fr.y, fr.z, fr.w};
    int r = i4 / 28, c0 = (i4 % 28) * 4;
    #pragma unroll
    for (int j = 0; j < 4; ++j){
      float t1 = ff[j]*aa[j]*sL;
      float t2 = rr[j]*aa[j]*sF;
      float y0 = rr[j] + A1*t1 + B1;
      float y1 = ff[j] + A2*t2 + B2;
      s0 += y0; q0 += y0*y0;
      s1 += y1; q1 += y1*y1;
      ys[0][r][c0+j] = f2bf(y0);
      ys[1][r][c0+j] = f2bf(y1);
    }
  }
  #pragma unroll
  for (int off = 32; off; off >>= 1){
    s0 += __shfl_xor(s0, off, 64); q0 += __shfl_xor(q0, off, 64);
    s1 += __shfl_xor(s1, off, 64); q1 += __shfl_xor(q1, off, 64);
  }
  if (lane == 0){ redA[w][0] = s0; redA[w][1] = q0; redA[w][2] = s1; redA[w][3] = q1; }
  __syncthreads();
  if (tid == 0){
    float a0=0,a1=0,a2=0,a3=0;
    for (int i = 0; i < 8; ++i){ a0+=redA[i][0]; a1+=redA[i][1]; a2+=redA[i][2]; a3+=redA[i][3]; }
    float4 ps = {a0,a1,a2,a3};
    planeStats[bc] = ps;
  }
  __syncthreads();

  const int kk[3] = {3,5,7};
  const int gg[3] = {37,22,16};
  for (int pl = 0; pl < 2; ++pl){
    const int cc = pl*64 + c;
    for (int ki = 0; ki < 3; ++ki){
      const int k = kk[ki], g = gg[ki];
      float sumAll = 0.f, mx = -3.0e38f;
      for (int win = tid; win < g*g; win += 512){
        int wy = win / g, wx = win % g;
        float s = 0.f;
        for (int dy = 0; dy < k; ++dy)
          for (int dx = 0; dx < k; ++dx)
            s += bf2f(ys[pl][wy*k+dy][wx*k+dx]);
        sumAll += s; mx = fmaxf(mx, s);
      }
      #pragma unroll
      for (int off = 32; off; off >>= 1){
        sumAll += __shfl_xor(sumAll, off, 64);
        mx = fmaxf(mx, __shfl_xor(mx, off, 64));
      }
      if (lane == 0){ redS[w] = sumAll; redM[w] = mx; }
      __syncthreads();
      if (tid == 0){
        float st = 0.f, mt = -3.0e38f;
        for (int i = 0; i < 8; ++i){ st += redS[i]; mt = fmaxf(mt, redM[i]); }
        int idx = (b*128 + cc)*3 + ki;
        avgstat[idx] = st / (float)(k*k*g*g);
        maxstat[idx] = mt / (float)(k*k);
      }
      __syncthreads();
    }
  }
}

// ---------------- K6: channel-attention MLP ----------------
__global__ void k6_mlp(const float* __restrict__ avgstat, const float* __restrict__ maxstat,
    const float* __restrict__ lin1, const float* __restrict__ lin2,
    const float* __restrict__ w1, const float* __restrict__ w2,
    float* __restrict__ ca)
{
  const int b = blockIdx.x, tid = threadIdx.x; // 128 threads
  __shared__ float sa[128], sm[128], hA[16], hM[16];
  int idx = (b*128 + tid)*3;
  sa[tid] = avgstat[idx]*lin1[0] + avgstat[idx+1]*lin1[1] + avgstat[idx+2]*lin1[2];
  sm[tid] = maxstat[idx]*lin2[0] + maxstat[idx+1]*lin2[1] + maxstat[idx+2]*lin2[2];
  __syncthreads();
  if (tid < 16){
    float ha = 0.f, hm = 0.f;
    for (int c2 = 0; c2 < 128; ++c2){
      ha += w1[tid*128 + c2]*sa[c2];
      hm += w1[tid*128 + c2]*sm[c2];
    }
    hA[tid] = fmaxf(ha, 0.f); hM[tid] = fmaxf(hm, 0.f);
  }
  __syncthreads();
  float o = 0.f;
  for (int r = 0; r < 16; ++r) o += w2[tid*16 + r]*(hA[r] + hM[r]);
  ca[b*128 + tid] = 1.f/(1.f + __expf(-o));
}

// ---------------- K8: final bn affine from per-plane stats + ca ----------------
__global__ void k8_affineF(const float4* __restrict__ planeStats, const float* __restrict__ ca,
    const float* __restrict__ rgb_cw, const float* __restrict__ rgb_bg, const float* __restrict__ rgb_bb,
    const float* __restrict__ fre_cw, const float* __restrict__ fre_bg, const float* __restrict__ fre_bb,
    float* __restrict__ ABF)
{
  int t = threadIdx.x;
  if (t >= 128) return;
  int z = t >> 6, c = t & 63;
  float S = 0.f, Q = 0.f;
  for (int b = 0; b < 32; ++b){
    float4 ps = planeStats[b*64 + c];
    float sc = ca[b*128 + t];
    float sp = z ? ps.z : ps.x;
    float qp = z ? ps.w : ps.y;
    S += sc*sp; Q += sc*sc*qp;
  }
  const float n = 401408.f;
  float m = S/n, v = Q/n - m*m;
  float cw = z ? fre_cw[c] : rgb_cw[c];
  float g  = z ? fre_bg[c] : rgb_bg[c];
  float bb = z ? fre_bb[c] : rgb_bb[c];
  float rs = rsqrtf(cw*cw*v + EPSV);
  ABF[z*128 + c]      = cw*rs*g;
  ABF[z*128 + 64 + c] = -cw*m*rs*g + bb;
}

// ---------------- K9: recompute y from attn, write both outputs ----------------
__global__ __launch_bounds__(256) void k9_out(
    const unsigned short* __restrict__ attn,
    const float* __restrict__ rgb, const float* __restrict__ fre,
    const float* __restrict__ AB1,
    const float* __restrict__ fad_gamma, const float* __restrict__ lfs_gamma,
    const float* __restrict__ ca, const float* __restrict__ ABF,
    float* __restrict__ out)
{
  const int c = blockIdx.x, b = blockIdx.y;
  const size_t plane = ((size_t)b*64 + c)*PP;
  const float sF = 2.f/(1.f + __expf(-fad_gamma[0])) - 1.f;
  const float sL = 2.f/(1.f + __expf(-lfs_gamma[0])) - 1.f;
  const float A1 = AB1[c], B1 = AB1[64+c], A2 = AB1[128+c], B2 = AB1[192+c];
  const float r_c = ca[b*128 + c], f_c = ca[b*128 + 64 + c];
  const float mul0 = 1.f + ABF[c]*r_c,        add0 = ABF[64 + c];
  const float mul1 = 1.f + ABF[128 + c]*f_c,  add1 = ABF[192 + c];
  float* o0 = out + plane;
  float* o1 = out + NE + plane;
  for (int i4 = threadIdx.x; i4 < 3136; i4 += 256){
    ushort4 av = *(const ushort4*)(attn + plane + (size_t)i4*4);
    float4 rg = *(const float4*)(rgb + plane + (size_t)i4*4);
    float4 fr = *(const float4*)(fre + plane + (size_t)i4*4);
    float aa[4] = {bf2f(av.x), bf2f(av.y), bf2f(av.z), bf2f(av.w)};
    float rr[4] = {rg.x, rg.y, rg.z, rg.w};
    float ff[4] = {fr.x, fr.y, fr.z, fr.w};
    float4 v0, v1;
    float* p0 = &v0.x; float* p1 = &v1.x;
    #pragma unroll
    for (int j = 0; j < 4; ++j){
      float t1 = ff[j]*aa[j]*sL;
      float t2 = rr[j]*aa[j]*sF;
      float y0 = rr[j] + A1*t1 + B1;
      float y1 = ff[j] + A2*t2 + B2;
      p0[j] = y0*mul0 + add0;
      p1[j] = y1*mul1 + add1;
    }
    *(float4*)(&o0[(size_t)i4*4]) = v0;
    *(float4*)(&o1[(size_t)i4*4]) = v1;
  }
}

extern "C" void kernel_launch(void* const* d_in, const int* in_sizes, int n_in,
                              void* d_out, int out_size, void* d_ws, size_t ws_size,
                              hipStream_t stream)
{
  (void)in_sizes; (void)n_in; (void)out_size; (void)ws_size;
  const float* rgb      = (const float*)d_in[0];
  const float* fre      = (const float*)d_in[1];
  const float* wq_fad   = (const float*)d_in[2];
  const float* bq_fad   = (const float*)d_in[3];
  const float* wq_lfs   = (const float*)d_in[4];
  const float* bq_lfs   = (const float*)d_in[5];
  const float* wk_fad   = (const float*)d_in[6];
  const float* bk_fad   = (const float*)d_in[7];
  const float* wk_lfs   = (const float*)d_in[8];
  const float* bk_lfs   = (const float*)d_in[9];
  const float* fad_gamma= (const float*)d_in[10];
  const float* lfs_gamma= (const float*)d_in[11];
  const float* fad_cw   = (const float*)d_in[12];
  const float* fad_bg   = (const float*)d_in[14];
  const float* fad_bb   = (const float*)d_in[15];
  const float* lfs_cw   = (const float*)d_in[16];
  const float* lfs_bg   = (const float*)d_in[18];
  const float* lfs_bb   = (const float*)d_in[19];
  const float* lin1_w   = (const float*)d_in[20];
  const float* lin2_w   = (const float*)d_in[21];
  const float* mlp_w1   = (const float*)d_in[22];
  const float* mlp_w2   = (const float*)d_in[23];
  const float* rgb_cw   = (const float*)d_in[24];
  const float* rgb_bg   = (const float*)d_in[26];
  const float* rgb_bb   = (const float*)d_in[27];
  const float* fre_cw   = (const float*)d_in[28];
  const float* fre_bg   = (const float*)d_in[30];
  const float* fre_bb   = (const float*)d_in[31];

  char* ws = (char*)d_ws;
  unsigned short* qF = (unsigned short*)(ws);          // becomes attn after k2
  unsigned short* qL = (unsigned short*)(ws + 2*NE);
  unsigned short* kF = (unsigned short*)(ws + 4*NE);
  unsigned short* kL = (unsigned short*)(ws + 6*NE);
  float* sbase = (float*)(ws + 8*NE);
  float* stats      = sbase;               // [0..255]   bn1 atomics (memset)
  float* AB1        = sbase + 256;
  float* avgstat    = sbase + 512;
  float* maxstat    = sbase + 12800;
  float* ca         = sbase + 25088;
  float* ABF        = sbase + 29184;
  float4* planeStats= (float4*)(sbase + 29440);

  hipMemsetAsync(stats, 0, 256*sizeof(float), stream);

  k1_conv<<<dim3(49,32,2), dim3(256), 0, stream>>>(rgb, fre,
      wq_fad, bq_fad, wk_fad, bk_fad, wq_lfs, bq_lfs, wk_lfs, bk_lfs,
      qF, kF, qL, kL);
  k2_attn<<<dim3(2048), dim3(448), 0, stream>>>(qF, qL, kF, kL,
      rgb, fre, fad_gamma, lfs_gamma, stats);
  k3_affine1<<<dim3(1), dim3(64), 0, stream>>>(stats,
      fad_cw, fad_bg, fad_bb, lfs_cw, lfs_bg, lfs_bb, AB1);
  k4_fuse<<<dim3(2048), dim3(512), 0, stream>>>((const unsigned short*)qF,
      rgb, fre, AB1, fad_gamma, lfs_gamma, avgstat, maxstat, planeStats);
  k6_mlp<<<dim3(32), dim3(128), 0, stream>>>(avgstat, maxstat,
      lin1_w, lin2_w, mlp_w1, mlp_w2, ca);
  k8_affineF<<<dim3(1), dim3(128), 0, stream>>>(planeStats, ca,
      rgb_cw, rgb_bg, rgb_bb, fre_cw, fre_bg, fre_bb, ABF);
  k9_out<<<dim3(64,32), dim3(256), 0, stream>>>((const unsigned short*)qF,
      rgb, fre, AB1, fad_gamma, lfs_gamma, ca, ABF, (float*)d_out);
}